// Round 1
// baseline (588.889 us; speedup 1.0000x reference)
//
#include <hip/hip_runtime.h>
#include <hip/hip_bf16.h>
#include <math.h>

#define BATCH 4096
#define TWO_B 8192
#define DIM 128
#define NB 16384
#define COS_EPS 1e-8f
#define LOSS_EPS 1e-6f
// 1/TEMP and log2(e)/TEMP
#define INV_TEMP 14.285714285714286f
#define EXP2_SCALE 20.60992915555662f

typedef __attribute__((ext_vector_type(8))) short bf16x8;
typedef __attribute__((ext_vector_type(4))) float f32x4;

// ---------------- K1: normalize rows, emit bf16 za_n + inverse norms ----------------
__global__ __launch_bounds__(256) void k_normalize(
    const float* __restrict__ z1, const float* __restrict__ z2,
    const float* __restrict__ zn,
    __hip_bfloat16* __restrict__ za_n, float* __restrict__ inv_za,
    float* __restrict__ inv_zn) {
  int wave = (blockIdx.x * blockDim.x + threadIdx.x) >> 6;
  int lane = threadIdx.x & 63;
  if (wave >= TWO_B + NB) return;
  const float* src;
  if (wave < BATCH) src = z1 + (size_t)wave * DIM;
  else if (wave < TWO_B) src = z2 + (size_t)(wave - BATCH) * DIM;
  else src = zn + (size_t)(wave - TWO_B) * DIM;
  float2 v = ((const float2*)src)[lane];
  float ss = v.x * v.x + v.y * v.y;
#pragma unroll
  for (int m = 1; m < 64; m <<= 1) ss += __shfl_xor(ss, m, 64);
  float inv = 1.0f / fmaxf(sqrtf(ss), COS_EPS);
  if (wave < TWO_B) {
    if (lane == 0) inv_za[wave] = inv;
    __hip_bfloat162 o;
    o.x = __float2bfloat16(v.x * inv);
    o.y = __float2bfloat16(v.y * inv);
    ((__hip_bfloat162*)(za_n + (size_t)wave * DIM))[lane] = o;
  } else {
    if (lane == 0) inv_zn[wave - TWO_B] = inv;
  }
}

// ---------------- K0: zero accumulators ----------------
__global__ __launch_bounds__(256) void k_zero(float* rowsum, float* acc) {
  int i = blockIdx.x * 256 + threadIdx.x;
  if (i < TWO_B) rowsum[i] = 0.0f;
  else if (i < TWO_B + 2) acc[i - TWO_B] = 0.0f;
}

// ---------------- K2: positives (fp32 exact dots) ----------------
__device__ __forceinline__ const float* za_row(const float* z1, const float* z2, int r) {
  return r < BATCH ? z1 + (size_t)r * DIM : z2 + (size_t)(r - BATCH) * DIM;
}

__global__ __launch_bounds__(256) void k_positives(
    const float* __restrict__ z1, const float* __restrict__ z2,
    const float* __restrict__ zn, const float* __restrict__ inv_za,
    const float* __restrict__ inv_zn, float* __restrict__ acc) {
  int wave = (blockIdx.x * blockDim.x + threadIdx.x) >> 6;
  int lane = threadIdx.x & 63;
  const int N_AUG = TWO_B;
  const int N_NEAR = 8 * BATCH;
  if (wave >= N_AUG + N_NEAR) return;
  const float *pa, *pb;
  float invprod;
  bool is_aug;
  if (wave < N_AUG) {
    int r = wave, p = (wave + BATCH) & (TWO_B - 1);
    pa = za_row(z1, z2, r);
    pb = za_row(z1, z2, p);
    invprod = inv_za[r] * inv_za[p];
    is_aug = true;
  } else {
    int k = wave - N_AUG;
    int zr, zc;
    if (k < BATCH)                { zr = BATCH + k; zc = k; }
    else if (k < BATCH + TWO_B)   { int j = k - BATCH;             zr = j; zc = j; }
    else if (k < BATCH + 2*TWO_B) { int j = k - BATCH - TWO_B;     zr = j; zc = j + BATCH; }
    else if (k < BATCH + 3*TWO_B) { int j = k - BATCH - 2*TWO_B;   zr = j; zc = j + 2*BATCH; }
    else                          { int j = k - BATCH - 3*TWO_B;   zr = j; zc = j + 3*BATCH; }
    pa = za_row(z1, z2, zr);
    pb = zn + (size_t)zc * DIM;
    invprod = inv_za[zr] * inv_zn[zc];
    is_aug = false;
  }
  float2 a = ((const float2*)pa)[lane];
  float2 b = ((const float2*)pb)[lane];
  float d = a.x * b.x + a.y * b.y;
#pragma unroll
  for (int m = 1; m < 64; m <<= 1) d += __shfl_xor(d, m, 64);
  if (lane == 0) {
    float sim = d * invprod;
    if (is_aug) atomicAdd(&acc[0], sim * INV_TEMP);
    else        atomicAdd(&acc[1], fminf(sim, 1.0f) * INV_TEMP);
  }
}

// ---------------- K3: Gram tile + fused exp2 row-sum (diag excluded) ----------------
// grid: (colsplit=16, rowblock=64); block 256 = 4 waves.
// Block tile: 128 rows x 512 cols (4 chunks of 128).
#define CCHUNKS 4
__global__ __launch_bounds__(256) void k_gram(
    const __hip_bfloat16* __restrict__ za_n, float* __restrict__ rowsum) {
  __shared__ char ldsA[32768];
  __shared__ char ldsB[32768];
  const int t = threadIdx.x;
  const int rowbase = blockIdx.y * 128;
  const int colbase0 = blockIdx.x * (CCHUNKS * 128);

  // stage A tile (128 rows x 128 k), XOR-swizzled
#pragma unroll
  for (int it = 0; it < 8; ++it) {
    int e = it * 2048 + t * 8;
    int row = e >> 7, k = e & 127;
    uint4 data = *(const uint4*)(za_n + (size_t)(rowbase + row) * DIM + k);
    *(uint4*)(ldsA + ((row * 256 + k * 2) ^ ((row & 7) << 4))) = data;
  }

  const int w = t >> 6, lane = t & 63;
  const int wrow = (w & 1) * 64, wcol = (w >> 1) * 64;
  const int lhi = lane >> 4, llo = lane & 15;

  float rp[4][4];
#pragma unroll
  for (int rt = 0; rt < 4; ++rt)
#pragma unroll
    for (int g = 0; g < 4; ++g) rp[rt][g] = 0.0f;

  for (int ch = 0; ch < CCHUNKS; ++ch) {
    const int colbase = colbase0 + ch * 128;
    __syncthreads();  // prior chunk's ldsB reads done
#pragma unroll
    for (int it = 0; it < 8; ++it) {
      int e = it * 2048 + t * 8;
      int row = e >> 7, k = e & 127;
      uint4 data = *(const uint4*)(za_n + (size_t)(colbase + row) * DIM + k);
      *(uint4*)(ldsB + ((row * 256 + k * 2) ^ ((row & 7) << 4))) = data;
    }
    __syncthreads();

    f32x4 acc[4][4];
#pragma unroll
    for (int rt = 0; rt < 4; ++rt)
#pragma unroll
      for (int ct = 0; ct < 4; ++ct) acc[rt][ct] = (f32x4)0.0f;

#pragma unroll
    for (int ks = 0; ks < 4; ++ks) {
      const int koff = ks * 32 + lhi * 8;
      bf16x8 afrag[4], bfrag[4];
#pragma unroll
      for (int rt = 0; rt < 4; ++rt) {
        int row = wrow + rt * 16 + llo;
        afrag[rt] = *(const bf16x8*)(ldsA + ((row * 256 + koff * 2) ^ ((row & 7) << 4)));
      }
#pragma unroll
      for (int ct = 0; ct < 4; ++ct) {
        int row = wcol + ct * 16 + llo;
        bfrag[ct] = *(const bf16x8*)(ldsB + ((row * 256 + koff * 2) ^ ((row & 7) << 4)));
      }
#pragma unroll
      for (int rt = 0; rt < 4; ++rt)
#pragma unroll
        for (int ct = 0; ct < 4; ++ct)
          acc[rt][ct] = __builtin_amdgcn_mfma_f32_16x16x32_bf16(
              afrag[rt], bfrag[ct], acc[rt][ct], 0, 0, 0);
    }

    // fused epilogue: exp2 + per-lane row partials, excluding the diagonal
#pragma unroll
    for (int rt = 0; rt < 4; ++rt) {
      const int grow = rowbase + wrow + rt * 16 + lhi * 4;  // + reg
#pragma unroll
      for (int ct = 0; ct < 4; ++ct) {
        const int gcol = colbase + wcol + ct * 16 + llo;
#pragma unroll
        for (int g = 0; g < 4; ++g) {
          float e = exp2f(acc[rt][ct][g] * EXP2_SCALE);
          if (grow + g != gcol) rp[rt][g] += e;
        }
      }
    }
  }

  // reduce the 16 lanes (llo) that share each row, then atomic per row
#pragma unroll
  for (int rt = 0; rt < 4; ++rt) {
#pragma unroll
    for (int g = 0; g < 4; ++g) {
      float s = rp[rt][g];
      s += __shfl_xor(s, 1, 64);
      s += __shfl_xor(s, 2, 64);
      s += __shfl_xor(s, 4, 64);
      s += __shfl_xor(s, 8, 64);
      if (llo == 0)
        atomicAdd(&rowsum[rowbase + wrow + rt * 16 + lhi * 4 + g], s);
    }
  }
}

// ---------------- K4: final scalar ----------------
__global__ __launch_bounds__(256) void k_final(
    const float* __restrict__ rowsum, const float* __restrict__ acc,
    float* __restrict__ out) {
  __shared__ float red[256];
  float s = 0.0f;
  for (int r = threadIdx.x; r < TWO_B; r += 256) s += logf(rowsum[r] + LOSS_EPS);
  red[threadIdx.x] = s;
  __syncthreads();
  for (int st = 128; st > 0; st >>= 1) {
    if (threadIdx.x < st) red[threadIdx.x] += red[threadIdx.x + st];
    __syncthreads();
  }
  if (threadIdx.x == 0)
    out[0] = (8.0f * red[0] - 4.0f * acc[0] - acc[1]) * (1.0f / 65536.0f);
}

extern "C" void kernel_launch(void* const* d_in, const int* in_sizes, int n_in,
                              void* d_out, int out_size, void* d_ws, size_t ws_size,
                              hipStream_t stream) {
  const float* z1 = (const float*)d_in[0];
  const float* z2 = (const float*)d_in[1];
  const float* zn = (const float*)d_in[2];
  float* out = (float*)d_out;

  char* ws = (char*)d_ws;
  __hip_bfloat16* za_n = (__hip_bfloat16*)ws;                      // 2 MB
  float* inv_za = (float*)(ws + 2097152);                          // 32 KB
  float* inv_zn = (float*)(ws + 2097152 + 32768);                  // 64 KB
  float* rowsum = (float*)(ws + 2097152 + 32768 + 65536);          // 32 KB
  float* acc    = (float*)(ws + 2097152 + 32768 + 65536 + 32768);  // 8 B

  // K1: normalize (24576 waves, 4/block)
  k_normalize<<<(TWO_B + NB) / 4, 256, 0, stream>>>(z1, z2, zn, za_n, inv_za, inv_zn);
  // K0: zero rowsum + acc
  k_zero<<<(TWO_B + 2 + 255) / 256, 256, 0, stream>>>(rowsum, acc);
  // K2: positives (8192 + 32768 waves, 4/block)
  k_positives<<<(TWO_B + 8 * BATCH) / 4, 256, 0, stream>>>(z1, z2, zn, inv_za, inv_zn, acc);
  // K3: gram row sums
  k_gram<<<dim3(16, 64), 256, 0, stream>>>(za_n, rowsum);
  // K4: final scalar
  k_final<<<1, 256, 0, stream>>>(rowsum, acc, out);
}

// Round 2
// 110.148 us; speedup vs baseline: 5.3463x; 5.3463x over previous
//
#include <hip/hip_runtime.h>
#include <hip/hip_bf16.h>
#include <math.h>

#define BATCH 4096
#define TWO_B 8192
#define DIM 128
#define NB 16384
#define COS_EPS 1e-8f
#define LOSS_EPS 1e-6f
// 1/TEMP and log2(e)/TEMP
#define INV_TEMP 14.285714285714286f
#define EXP2_SCALE 20.60992915555662f

#define N_POS_WAVES (TWO_B + 8 * BATCH)   // 40960

typedef __attribute__((ext_vector_type(8))) short bf16x8;
typedef __attribute__((ext_vector_type(4))) float f32x4;

// ---------------- K1: normalize rows, emit bf16 za_n + inverse norms ----------------
__global__ __launch_bounds__(256) void k_normalize(
    const float* __restrict__ z1, const float* __restrict__ z2,
    const float* __restrict__ zn,
    __hip_bfloat16* __restrict__ za_n, float* __restrict__ inv_za,
    float* __restrict__ inv_zn) {
  int wave = (blockIdx.x * blockDim.x + threadIdx.x) >> 6;
  int lane = threadIdx.x & 63;
  if (wave >= TWO_B + NB) return;
  const float* src;
  if (wave < BATCH) src = z1 + (size_t)wave * DIM;
  else if (wave < TWO_B) src = z2 + (size_t)(wave - BATCH) * DIM;
  else src = zn + (size_t)(wave - TWO_B) * DIM;
  float2 v = ((const float2*)src)[lane];
  float ss = v.x * v.x + v.y * v.y;
#pragma unroll
  for (int m = 1; m < 64; m <<= 1) ss += __shfl_xor(ss, m, 64);
  float inv = 1.0f / fmaxf(sqrtf(ss), COS_EPS);
  if (wave < TWO_B) {
    if (lane == 0) inv_za[wave] = inv;
    __hip_bfloat162 o;
    o.x = __float2bfloat16(v.x * inv);
    o.y = __float2bfloat16(v.y * inv);
    ((__hip_bfloat162*)(za_n + (size_t)wave * DIM))[lane] = o;
  } else {
    if (lane == 0) inv_zn[wave - TWO_B] = inv;
  }
}

// ---------------- K0: zero rowsum ----------------
__global__ __launch_bounds__(256) void k_zero(float* rowsum) {
  int i = blockIdx.x * 256 + threadIdx.x;
  if (i < TWO_B) rowsum[i] = 0.0f;
}

// ---------------- K2: positives (fp32 exact dots, no contended atomics) ----------------
__device__ __forceinline__ const float* za_row(const float* z1, const float* z2, int r) {
  return r < BATCH ? z1 + (size_t)r * DIM : z2 + (size_t)(r - BATCH) * DIM;
}

__global__ __launch_bounds__(256) void k_positives(
    const float* __restrict__ z1, const float* __restrict__ z2,
    const float* __restrict__ zn, const float* __restrict__ inv_za,
    const float* __restrict__ inv_zn, float* __restrict__ pos_partial) {
  int wave = (blockIdx.x * blockDim.x + threadIdx.x) >> 6;
  int lane = threadIdx.x & 63;
  const int N_AUG = TWO_B;
  if (wave >= N_POS_WAVES) return;
  const float *pa, *pb;
  float invprod;
  bool is_aug;
  if (wave < N_AUG) {
    int r = wave, p = (wave + BATCH) & (TWO_B - 1);
    pa = za_row(z1, z2, r);
    pb = za_row(z1, z2, p);
    invprod = inv_za[r] * inv_za[p];
    is_aug = true;
  } else {
    int k = wave - N_AUG;
    int zr, zc;
    if (k < BATCH)                { zr = BATCH + k; zc = k; }
    else if (k < BATCH + TWO_B)   { int j = k - BATCH;             zr = j; zc = j; }
    else if (k < BATCH + 2*TWO_B) { int j = k - BATCH - TWO_B;     zr = j; zc = j + BATCH; }
    else if (k < BATCH + 3*TWO_B) { int j = k - BATCH - 2*TWO_B;   zr = j; zc = j + 2*BATCH; }
    else                          { int j = k - BATCH - 3*TWO_B;   zr = j; zc = j + 3*BATCH; }
    pa = za_row(z1, z2, zr);
    pb = zn + (size_t)zc * DIM;
    invprod = inv_za[zr] * inv_zn[zc];
    is_aug = false;
  }
  float2 a = ((const float2*)pa)[lane];
  float2 b = ((const float2*)pb)[lane];
  float d = a.x * b.x + a.y * b.y;
#pragma unroll
  for (int m = 1; m < 64; m <<= 1) d += __shfl_xor(d, m, 64);
  if (lane == 0) {
    float sim = d * invprod;
    // weighted term; k_final sums all of these and subtracts
    pos_partial[wave] = is_aug ? (4.0f * sim * INV_TEMP)
                               : (fminf(sim, 1.0f) * INV_TEMP);
  }
}

// ---------------- K3: Gram tile + fused exp2 row-sum (diag excluded) ----------------
// grid: (colsplit=16, rowblock=64); block 256 = 4 waves.
// Block tile: 128 rows x 512 cols (4 chunks of 128).
#define CCHUNKS 4
__global__ __launch_bounds__(256) void k_gram(
    const __hip_bfloat16* __restrict__ za_n, float* __restrict__ rowsum) {
  __shared__ char ldsA[32768];
  __shared__ char ldsB[32768];
  const int t = threadIdx.x;
  const int rowbase = blockIdx.y * 128;
  const int colbase0 = blockIdx.x * (CCHUNKS * 128);

  // stage A tile (128 rows x 128 k), XOR-swizzled
#pragma unroll
  for (int it = 0; it < 8; ++it) {
    int e = it * 2048 + t * 8;
    int row = e >> 7, k = e & 127;
    uint4 data = *(const uint4*)(za_n + (size_t)(rowbase + row) * DIM + k);
    *(uint4*)(ldsA + ((row * 256 + k * 2) ^ ((row & 7) << 4))) = data;
  }

  const int w = t >> 6, lane = t & 63;
  const int wrow = (w & 1) * 64, wcol = (w >> 1) * 64;
  const int lhi = lane >> 4, llo = lane & 15;

  float rp[4][4];
#pragma unroll
  for (int rt = 0; rt < 4; ++rt)
#pragma unroll
    for (int g = 0; g < 4; ++g) rp[rt][g] = 0.0f;

  for (int ch = 0; ch < CCHUNKS; ++ch) {
    const int colbase = colbase0 + ch * 128;
    __syncthreads();  // prior chunk's ldsB reads done
#pragma unroll
    for (int it = 0; it < 8; ++it) {
      int e = it * 2048 + t * 8;
      int row = e >> 7, k = e & 127;
      uint4 data = *(const uint4*)(za_n + (size_t)(colbase + row) * DIM + k);
      *(uint4*)(ldsB + ((row * 256 + k * 2) ^ ((row & 7) << 4))) = data;
    }
    __syncthreads();

    f32x4 acc[4][4];
#pragma unroll
    for (int rt = 0; rt < 4; ++rt)
#pragma unroll
      for (int ct = 0; ct < 4; ++ct) acc[rt][ct] = (f32x4)0.0f;

#pragma unroll
    for (int ks = 0; ks < 4; ++ks) {
      const int koff = ks * 32 + lhi * 8;
      bf16x8 afrag[4], bfrag[4];
#pragma unroll
      for (int rt = 0; rt < 4; ++rt) {
        int row = wrow + rt * 16 + llo;
        afrag[rt] = *(const bf16x8*)(ldsA + ((row * 256 + koff * 2) ^ ((row & 7) << 4)));
      }
#pragma unroll
      for (int ct = 0; ct < 4; ++ct) {
        int row = wcol + ct * 16 + llo;
        bfrag[ct] = *(const bf16x8*)(ldsB + ((row * 256 + koff * 2) ^ ((row & 7) << 4)));
      }
#pragma unroll
      for (int rt = 0; rt < 4; ++rt)
#pragma unroll
        for (int ct = 0; ct < 4; ++ct)
          acc[rt][ct] = __builtin_amdgcn_mfma_f32_16x16x32_bf16(
              afrag[rt], bfrag[ct], acc[rt][ct], 0, 0, 0);
    }

    // fused epilogue: exp2 + per-lane row partials, excluding the diagonal
#pragma unroll
    for (int rt = 0; rt < 4; ++rt) {
      const int grow = rowbase + wrow + rt * 16 + lhi * 4;  // + reg
#pragma unroll
      for (int ct = 0; ct < 4; ++ct) {
        const int gcol = colbase + wcol + ct * 16 + llo;
#pragma unroll
        for (int g = 0; g < 4; ++g) {
          float e = exp2f(acc[rt][ct][g] * EXP2_SCALE);
          if (grow + g != gcol) rp[rt][g] += e;
        }
      }
    }
  }

  // reduce the 16 lanes (llo) that share each row, then atomic per row
#pragma unroll
  for (int rt = 0; rt < 4; ++rt) {
#pragma unroll
    for (int g = 0; g < 4; ++g) {
      float s = rp[rt][g];
      s += __shfl_xor(s, 1, 64);
      s += __shfl_xor(s, 2, 64);
      s += __shfl_xor(s, 4, 64);
      s += __shfl_xor(s, 8, 64);
      if (llo == 0)
        atomicAdd(&rowsum[rowbase + wrow + rt * 16 + lhi * 4 + g], s);
    }
  }
}

// ---------------- K4: final scalar ----------------
__global__ __launch_bounds__(256) void k_final(
    const float* __restrict__ rowsum, const float* __restrict__ pos_partial,
    float* __restrict__ out) {
  __shared__ float red[256];
  float s = 0.0f;
  for (int r = threadIdx.x; r < TWO_B; r += 256) s += 8.0f * logf(rowsum[r] + LOSS_EPS);
  for (int k = threadIdx.x; k < N_POS_WAVES; k += 256) s -= pos_partial[k];
  red[threadIdx.x] = s;
  __syncthreads();
  for (int st = 128; st > 0; st >>= 1) {
    if (threadIdx.x < st) red[threadIdx.x] += red[threadIdx.x + st];
    __syncthreads();
  }
  if (threadIdx.x == 0)
    out[0] = red[0] * (1.0f / 65536.0f);
}

extern "C" void kernel_launch(void* const* d_in, const int* in_sizes, int n_in,
                              void* d_out, int out_size, void* d_ws, size_t ws_size,
                              hipStream_t stream) {
  const float* z1 = (const float*)d_in[0];
  const float* z2 = (const float*)d_in[1];
  const float* zn = (const float*)d_in[2];
  float* out = (float*)d_out;

  char* ws = (char*)d_ws;
  __hip_bfloat16* za_n = (__hip_bfloat16*)ws;                       // 2 MB
  float* inv_za = (float*)(ws + 2097152);                           // 32 KB
  float* inv_zn = (float*)(ws + 2097152 + 32768);                   // 64 KB
  float* rowsum = (float*)(ws + 2097152 + 32768 + 65536);           // 32 KB
  float* pos_partial = (float*)(ws + 2097152 + 32768 + 65536 + 32768); // 160 KB

  // K1: normalize (24576 waves, 4/block)
  k_normalize<<<(TWO_B + NB) / 4, 256, 0, stream>>>(z1, z2, zn, za_n, inv_za, inv_zn);
  // K0: zero rowsum
  k_zero<<<(TWO_B + 255) / 256, 256, 0, stream>>>(rowsum);
  // K2: positives (8192 + 32768 waves, 4/block) -> private partial slots
  k_positives<<<N_POS_WAVES / 4, 256, 0, stream>>>(z1, z2, zn, inv_za, inv_zn, pos_partial);
  // K3: gram row sums
  k_gram<<<dim3(16, 64), 256, 0, stream>>>(za_n, rowsum);
  // K4: final scalar
  k_final<<<1, 256, 0, stream>>>(rowsum, pos_partial, out);
}

// Round 3
// 65.904 us; speedup vs baseline: 8.9356x; 1.6714x over previous
//
#include <hip/hip_runtime.h>
#include <hip/hip_bf16.h>
#include <math.h>

#define BATCH 4096
#define TWO_B 8192
#define DIM 128
#define NB 16384
#define COS_EPS 1e-8f
#define LOSS_EPS 1e-6f
// 1/TEMP and log2(e)/TEMP
#define INV_TEMP 14.285714285714286f
#define EXP2_SCALE 20.60992915555662f

#define N_POS_WAVES (TWO_B + 8 * BATCH)   // 40960
#define RED_BLOCKS 64

typedef __attribute__((ext_vector_type(8))) short bf16x8;
typedef __attribute__((ext_vector_type(4))) float f32x4;

// ---------------- K1: normalize rows, emit bf16 za_n + inverse norms ----------------
__global__ __launch_bounds__(256) void k_normalize(
    const float* __restrict__ z1, const float* __restrict__ z2,
    const float* __restrict__ zn,
    __hip_bfloat16* __restrict__ za_n, float* __restrict__ inv_za,
    float* __restrict__ inv_zn) {
  int wave = (blockIdx.x * blockDim.x + threadIdx.x) >> 6;
  int lane = threadIdx.x & 63;
  if (wave >= TWO_B + NB) return;
  const float* src;
  if (wave < BATCH) src = z1 + (size_t)wave * DIM;
  else if (wave < TWO_B) src = z2 + (size_t)(wave - BATCH) * DIM;
  else src = zn + (size_t)(wave - TWO_B) * DIM;
  float2 v = ((const float2*)src)[lane];
  float ss = v.x * v.x + v.y * v.y;
#pragma unroll
  for (int m = 1; m < 64; m <<= 1) ss += __shfl_xor(ss, m, 64);
  float inv = 1.0f / fmaxf(sqrtf(ss), COS_EPS);
  if (wave < TWO_B) {
    if (lane == 0) inv_za[wave] = inv;
    __hip_bfloat162 o;
    o.x = __float2bfloat16(v.x * inv);
    o.y = __float2bfloat16(v.y * inv);
    ((__hip_bfloat162*)(za_n + (size_t)wave * DIM))[lane] = o;
  } else {
    if (lane == 0) inv_zn[wave - TWO_B] = inv;
  }
}

// ---------------- K0: zero rowsum ----------------
__global__ __launch_bounds__(256) void k_zero(float* rowsum) {
  int i = blockIdx.x * 256 + threadIdx.x;
  if (i < TWO_B) rowsum[i] = 0.0f;
}

// ---------------- K2: positives (fp32 exact dots, no contended atomics) ----------------
__device__ __forceinline__ const float* za_row(const float* z1, const float* z2, int r) {
  return r < BATCH ? z1 + (size_t)r * DIM : z2 + (size_t)(r - BATCH) * DIM;
}

__global__ __launch_bounds__(256) void k_positives(
    const float* __restrict__ z1, const float* __restrict__ z2,
    const float* __restrict__ zn, const float* __restrict__ inv_za,
    const float* __restrict__ inv_zn, float* __restrict__ pos_partial) {
  int wave = (blockIdx.x * blockDim.x + threadIdx.x) >> 6;
  int lane = threadIdx.x & 63;
  const int N_AUG = TWO_B;
  if (wave >= N_POS_WAVES) return;
  const float *pa, *pb;
  float invprod;
  bool is_aug;
  if (wave < N_AUG) {
    int r = wave, p = (wave + BATCH) & (TWO_B - 1);
    pa = za_row(z1, z2, r);
    pb = za_row(z1, z2, p);
    invprod = inv_za[r] * inv_za[p];
    is_aug = true;
  } else {
    int k = wave - N_AUG;
    int zr, zc;
    if (k < BATCH)                { zr = BATCH + k; zc = k; }
    else if (k < BATCH + TWO_B)   { int j = k - BATCH;             zr = j; zc = j; }
    else if (k < BATCH + 2*TWO_B) { int j = k - BATCH - TWO_B;     zr = j; zc = j + BATCH; }
    else if (k < BATCH + 3*TWO_B) { int j = k - BATCH - 2*TWO_B;   zr = j; zc = j + 2*BATCH; }
    else                          { int j = k - BATCH - 3*TWO_B;   zr = j; zc = j + 3*BATCH; }
    pa = za_row(z1, z2, zr);
    pb = zn + (size_t)zc * DIM;
    invprod = inv_za[zr] * inv_zn[zc];
    is_aug = false;
  }
  float2 a = ((const float2*)pa)[lane];
  float2 b = ((const float2*)pb)[lane];
  float d = a.x * b.x + a.y * b.y;
#pragma unroll
  for (int m = 1; m < 64; m <<= 1) d += __shfl_xor(d, m, 64);
  if (lane == 0) {
    float sim = d * invprod;
    pos_partial[wave] = is_aug ? (4.0f * sim * INV_TEMP)
                               : (fminf(sim, 1.0f) * INV_TEMP);
  }
}

// ---------------- K3: Gram tile + fused exp2 row-sum (diag excluded) ----------------
#define CCHUNKS 4
__global__ __launch_bounds__(256) void k_gram(
    const __hip_bfloat16* __restrict__ za_n, float* __restrict__ rowsum) {
  __shared__ char ldsA[32768];
  __shared__ char ldsB[32768];
  const int t = threadIdx.x;
  const int rowbase = blockIdx.y * 128;
  const int colbase0 = blockIdx.x * (CCHUNKS * 128);

#pragma unroll
  for (int it = 0; it < 8; ++it) {
    int e = it * 2048 + t * 8;
    int row = e >> 7, k = e & 127;
    uint4 data = *(const uint4*)(za_n + (size_t)(rowbase + row) * DIM + k);
    *(uint4*)(ldsA + ((row * 256 + k * 2) ^ ((row & 7) << 4))) = data;
  }

  const int w = t >> 6, lane = t & 63;
  const int wrow = (w & 1) * 64, wcol = (w >> 1) * 64;
  const int lhi = lane >> 4, llo = lane & 15;

  float rp[4][4];
#pragma unroll
  for (int rt = 0; rt < 4; ++rt)
#pragma unroll
    for (int g = 0; g < 4; ++g) rp[rt][g] = 0.0f;

  for (int ch = 0; ch < CCHUNKS; ++ch) {
    const int colbase = colbase0 + ch * 128;
    __syncthreads();
#pragma unroll
    for (int it = 0; it < 8; ++it) {
      int e = it * 2048 + t * 8;
      int row = e >> 7, k = e & 127;
      uint4 data = *(const uint4*)(za_n + (size_t)(colbase + row) * DIM + k);
      *(uint4*)(ldsB + ((row * 256 + k * 2) ^ ((row & 7) << 4))) = data;
    }
    __syncthreads();

    f32x4 acc[4][4];
#pragma unroll
    for (int rt = 0; rt < 4; ++rt)
#pragma unroll
      for (int ct = 0; ct < 4; ++ct) acc[rt][ct] = (f32x4)0.0f;

#pragma unroll
    for (int ks = 0; ks < 4; ++ks) {
      const int koff = ks * 32 + lhi * 8;
      bf16x8 afrag[4], bfrag[4];
#pragma unroll
      for (int rt = 0; rt < 4; ++rt) {
        int row = wrow + rt * 16 + llo;
        afrag[rt] = *(const bf16x8*)(ldsA + ((row * 256 + koff * 2) ^ ((row & 7) << 4)));
      }
#pragma unroll
      for (int ct = 0; ct < 4; ++ct) {
        int row = wcol + ct * 16 + llo;
        bfrag[ct] = *(const bf16x8*)(ldsB + ((row * 256 + koff * 2) ^ ((row & 7) << 4)));
      }
#pragma unroll
      for (int rt = 0; rt < 4; ++rt)
#pragma unroll
        for (int ct = 0; ct < 4; ++ct)
          acc[rt][ct] = __builtin_amdgcn_mfma_f32_16x16x32_bf16(
              afrag[rt], bfrag[ct], acc[rt][ct], 0, 0, 0);
    }

#pragma unroll
    for (int rt = 0; rt < 4; ++rt) {
      const int grow = rowbase + wrow + rt * 16 + lhi * 4;
#pragma unroll
      for (int ct = 0; ct < 4; ++ct) {
        const int gcol = colbase + wcol + ct * 16 + llo;
#pragma unroll
        for (int g = 0; g < 4; ++g) {
          float e = exp2f(acc[rt][ct][g] * EXP2_SCALE);
          if (grow + g != gcol) rp[rt][g] += e;
        }
      }
    }
  }

#pragma unroll
  for (int rt = 0; rt < 4; ++rt) {
#pragma unroll
    for (int g = 0; g < 4; ++g) {
      float s = rp[rt][g];
      s += __shfl_xor(s, 1, 64);
      s += __shfl_xor(s, 2, 64);
      s += __shfl_xor(s, 4, 64);
      s += __shfl_xor(s, 8, 64);
      if (llo == 0)
        atomicAdd(&rowsum[rowbase + wrow + rt * 16 + lhi * 4 + g], s);
    }
  }
}

// ---------------- K4a: parallel reduction stage 1 ----------------
__global__ __launch_bounds__(256) void k_reduce(
    const float* __restrict__ rowsum, const float* __restrict__ pos_partial,
    float* __restrict__ blkpart) {
  __shared__ float red[256];
  const int gid = blockIdx.x * 256 + threadIdx.x;
  const int stride = RED_BLOCKS * 256;
  float s = 0.0f;
  for (int r = gid; r < TWO_B; r += stride) s += 8.0f * logf(rowsum[r] + LOSS_EPS);
  for (int k = gid; k < N_POS_WAVES; k += stride) s -= pos_partial[k];
  red[threadIdx.x] = s;
  __syncthreads();
  for (int st = 128; st > 0; st >>= 1) {
    if (threadIdx.x < st) red[threadIdx.x] += red[threadIdx.x + st];
    __syncthreads();
  }
  if (threadIdx.x == 0) blkpart[blockIdx.x] = red[0];
}

// ---------------- K4b: final scalar ----------------
__global__ __launch_bounds__(64) void k_final(
    const float* __restrict__ blkpart, float* __restrict__ out) {
  float s = threadIdx.x < RED_BLOCKS ? blkpart[threadIdx.x] : 0.0f;
#pragma unroll
  for (int m = 1; m < 64; m <<= 1) s += __shfl_xor(s, m, 64);
  if (threadIdx.x == 0) out[0] = s * (1.0f / 65536.0f);
}

extern "C" void kernel_launch(void* const* d_in, const int* in_sizes, int n_in,
                              void* d_out, int out_size, void* d_ws, size_t ws_size,
                              hipStream_t stream) {
  const float* z1 = (const float*)d_in[0];
  const float* z2 = (const float*)d_in[1];
  const float* zn = (const float*)d_in[2];
  float* out = (float*)d_out;

  char* ws = (char*)d_ws;
  __hip_bfloat16* za_n = (__hip_bfloat16*)ws;                          // 2 MB
  float* inv_za = (float*)(ws + 2097152);                              // 32 KB
  float* inv_zn = (float*)(ws + 2097152 + 32768);                      // 64 KB
  float* rowsum = (float*)(ws + 2097152 + 32768 + 65536);              // 32 KB
  float* pos_partial = (float*)(ws + 2097152 + 32768 + 65536 + 32768); // 160 KB
  float* blkpart = (float*)(ws + 2097152 + 32768 + 65536 + 32768 + 163840); // 256 B

  k_normalize<<<(TWO_B + NB) / 4, 256, 0, stream>>>(z1, z2, zn, za_n, inv_za, inv_zn);
  k_zero<<<(TWO_B + 255) / 256, 256, 0, stream>>>(rowsum);
  k_positives<<<N_POS_WAVES / 4, 256, 0, stream>>>(z1, z2, zn, inv_za, inv_zn, pos_partial);
  k_gram<<<dim3(16, 64), 256, 0, stream>>>(za_n, rowsum);
  k_reduce<<<RED_BLOCKS, 256, 0, stream>>>(rowsum, pos_partial, blkpart);
  k_final<<<1, 64, 0, stream>>>(blkpart, out);
}

// Round 4
// 54.622 us; speedup vs baseline: 10.7812x; 1.2065x over previous
//
#include <hip/hip_runtime.h>
#include <hip/hip_bf16.h>
#include <math.h>

#define BATCH 4096
#define TWO_B 8192
#define DIM 128
#define NB 16384
#define COS_EPS 1e-8f
#define LOSS_EPS 1e-6f
// 1/TEMP ; log2(e)/TEMP ; sqrt(log2(e)/TEMP)
#define INV_TEMP 14.285714285714286f
#define EXP2_SCALE 20.60992915555662f
#define SQRT_EXP2_SCALE 4.5398166f

#define N_POS_WAVES (TWO_B + 8 * BATCH)   // 40960
#define RED_BLOCKS 64

typedef __attribute__((ext_vector_type(8))) short bf16x8;
typedef __attribute__((ext_vector_type(4))) float f32x4;

__device__ __forceinline__ float fast_exp2(float x) {
#if __has_builtin(__builtin_amdgcn_exp2f)
  return __builtin_amdgcn_exp2f(x);
#else
  float r;
  asm("v_exp_f32 %0, %1" : "=v"(r) : "v"(x));
  return r;
#endif
}

// ---------------- K1: normalize rows, emit bf16 za_n (pre-scaled by sqrt(EXP2_SCALE)) ----------------
__global__ __launch_bounds__(256) void k_normalize(
    const float* __restrict__ z1, const float* __restrict__ z2,
    const float* __restrict__ zn,
    __hip_bfloat16* __restrict__ za_n, float* __restrict__ inv_za,
    float* __restrict__ inv_zn) {
  int wave = (blockIdx.x * blockDim.x + threadIdx.x) >> 6;
  int lane = threadIdx.x & 63;
  if (wave >= TWO_B + NB) return;
  const float* src;
  if (wave < BATCH) src = z1 + (size_t)wave * DIM;
  else if (wave < TWO_B) src = z2 + (size_t)(wave - BATCH) * DIM;
  else src = zn + (size_t)(wave - TWO_B) * DIM;
  float2 v = ((const float2*)src)[lane];
  float ss = v.x * v.x + v.y * v.y;
#pragma unroll
  for (int m = 1; m < 64; m <<= 1) ss += __shfl_xor(ss, m, 64);
  float inv = 1.0f / fmaxf(sqrtf(ss), COS_EPS);
  if (wave < TWO_B) {
    if (lane == 0) inv_za[wave] = inv;
    float s = inv * SQRT_EXP2_SCALE;   // fold exp2 scale into the data
    __hip_bfloat162 o;
    o.x = __float2bfloat16(v.x * s);
    o.y = __float2bfloat16(v.y * s);
    ((__hip_bfloat162*)(za_n + (size_t)wave * DIM))[lane] = o;
  } else {
    if (lane == 0) inv_zn[wave - TWO_B] = inv;
  }
}

// ---------------- K0: zero rowsum ----------------
__global__ __launch_bounds__(256) void k_zero(float* rowsum) {
  int i = blockIdx.x * 256 + threadIdx.x;
  if (i < TWO_B) rowsum[i] = 0.0f;
}

// ---------------- K2: positives (fp32 exact dots, private partial slots) ----------------
__device__ __forceinline__ const float* za_row(const float* z1, const float* z2, int r) {
  return r < BATCH ? z1 + (size_t)r * DIM : z2 + (size_t)(r - BATCH) * DIM;
}

__global__ __launch_bounds__(256) void k_positives(
    const float* __restrict__ z1, const float* __restrict__ z2,
    const float* __restrict__ zn, const float* __restrict__ inv_za,
    const float* __restrict__ inv_zn, float* __restrict__ pos_partial) {
  int wave = (blockIdx.x * blockDim.x + threadIdx.x) >> 6;
  int lane = threadIdx.x & 63;
  const int N_AUG = TWO_B;
  if (wave >= N_POS_WAVES) return;
  const float *pa, *pb;
  float invprod;
  bool is_aug;
  if (wave < N_AUG) {
    int r = wave, p = (wave + BATCH) & (TWO_B - 1);
    pa = za_row(z1, z2, r);
    pb = za_row(z1, z2, p);
    invprod = inv_za[r] * inv_za[p];
    is_aug = true;
  } else {
    int k = wave - N_AUG;
    int zr, zc;
    if (k < BATCH)                { zr = BATCH + k; zc = k; }
    else if (k < BATCH + TWO_B)   { int j = k - BATCH;             zr = j; zc = j; }
    else if (k < BATCH + 2*TWO_B) { int j = k - BATCH - TWO_B;     zr = j; zc = j + BATCH; }
    else if (k < BATCH + 3*TWO_B) { int j = k - BATCH - 2*TWO_B;   zr = j; zc = j + 2*BATCH; }
    else                          { int j = k - BATCH - 3*TWO_B;   zr = j; zc = j + 3*BATCH; }
    pa = za_row(z1, z2, zr);
    pb = zn + (size_t)zc * DIM;
    invprod = inv_za[zr] * inv_zn[zc];
    is_aug = false;
  }
  float2 a = ((const float2*)pa)[lane];
  float2 b = ((const float2*)pb)[lane];
  float d = a.x * b.x + a.y * b.y;
#pragma unroll
  for (int m = 1; m < 64; m <<= 1) d += __shfl_xor(d, m, 64);
  if (lane == 0) {
    float sim = d * invprod;
    pos_partial[wave] = is_aug ? (4.0f * sim * INV_TEMP)
                               : (fminf(sim, 1.0f) * INV_TEMP);
  }
}

// ---------------- K3: symmetric Gram + fused exp2 row/col sums ----------------
// grid: (colgroup=16, rowtile=64); block 256 = 4 waves; tile 128 rows x 4x128 cols.
// Only chunks with col-tile >= row-tile are computed; off-diagonal tiles feed both
// rowsum[rows] (row sums) and rowsum[cols] (col sums, by symmetry).
__global__ __launch_bounds__(256) void k_gram(
    const __hip_bfloat16* __restrict__ za_n, float* __restrict__ rowsum) {
  __shared__ char ldsA[32768];
  __shared__ char ldsB[32768];
  const int t = threadIdx.x;
  const int itile = blockIdx.y;        // row tile (128 rows)
  const int c0 = blockIdx.x * 4;       // first col tile of this group
  if (c0 + 3 < itile) return;          // entirely below diagonal
  const int rowbase = itile * 128;

  // stage A tile (128 rows x 128 k), XOR-swizzled
#pragma unroll
  for (int it = 0; it < 8; ++it) {
    int e = it * 2048 + t * 8;
    int row = e >> 7, k = e & 127;
    uint4 data = *(const uint4*)(za_n + (size_t)(rowbase + row) * DIM + k);
    *(uint4*)(ldsA + ((row * 256 + k * 2) ^ ((row & 7) << 4))) = data;
  }

  const int w = t >> 6, lane = t & 63;
  const int wrow = (w & 1) * 64, wcol = (w >> 1) * 64;
  const int lhi = lane >> 4, llo = lane & 15;

  float rowp[4][4];
#pragma unroll
  for (int rt = 0; rt < 4; ++rt)
#pragma unroll
    for (int g = 0; g < 4; ++g) rowp[rt][g] = 0.0f;

  for (int ch = 0; ch < 4; ++ch) {
    const int ctile = c0 + ch;
    if (ctile < itile) continue;       // block-uniform: barrier-safe
    const int colbase = ctile * 128;
    __syncthreads();                   // prior chunk's ldsB reads done
#pragma unroll
    for (int it = 0; it < 8; ++it) {
      int e = it * 2048 + t * 8;
      int row = e >> 7, k = e & 127;
      uint4 data = *(const uint4*)(za_n + (size_t)(colbase + row) * DIM + k);
      *(uint4*)(ldsB + ((row * 256 + k * 2) ^ ((row & 7) << 4))) = data;
    }
    __syncthreads();

    f32x4 acc[4][4];
#pragma unroll
    for (int rt = 0; rt < 4; ++rt)
#pragma unroll
      for (int ct = 0; ct < 4; ++ct) acc[rt][ct] = (f32x4)0.0f;

#pragma unroll
    for (int ks = 0; ks < 4; ++ks) {
      const int koff = ks * 32 + lhi * 8;
      bf16x8 afrag[4], bfrag[4];
#pragma unroll
      for (int rt = 0; rt < 4; ++rt) {
        int row = wrow + rt * 16 + llo;
        afrag[rt] = *(const bf16x8*)(ldsA + ((row * 256 + koff * 2) ^ ((row & 7) << 4)));
      }
#pragma unroll
      for (int ct = 0; ct < 4; ++ct) {
        int row = wcol + ct * 16 + llo;
        bfrag[ct] = *(const bf16x8*)(ldsB + ((row * 256 + koff * 2) ^ ((row & 7) << 4)));
      }
#pragma unroll
      for (int rt = 0; rt < 4; ++rt)
#pragma unroll
        for (int ct = 0; ct < 4; ++ct)
          acc[rt][ct] = __builtin_amdgcn_mfma_f32_16x16x32_bf16(
              afrag[rt], bfrag[ct], acc[rt][ct], 0, 0, 0);
    }

    if (ctile == itile) {
      // diagonal tile: row sums only, diagonal excluded by index
#pragma unroll
      for (int rt = 0; rt < 4; ++rt) {
        const int lrow = wrow + rt * 16 + lhi * 4;
#pragma unroll
        for (int ct = 0; ct < 4; ++ct) {
          const int lcol = wcol + ct * 16 + llo;
#pragma unroll
          for (int g = 0; g < 4; ++g) {
            float e = fast_exp2(acc[rt][ct][g]);
            if (lrow + g != lcol) rowp[rt][g] += e;
          }
        }
      }
    } else {
      // off-diagonal: row sums + column sums (symmetry)
      float colp[4] = {0.0f, 0.0f, 0.0f, 0.0f};
#pragma unroll
      for (int rt = 0; rt < 4; ++rt)
#pragma unroll
        for (int ct = 0; ct < 4; ++ct)
#pragma unroll
          for (int g = 0; g < 4; ++g) {
            float e = fast_exp2(acc[rt][ct][g]);
            rowp[rt][g] += e;
            colp[ct] += e;
          }
#pragma unroll
      for (int ct = 0; ct < 4; ++ct) {
        float cs = colp[ct];
        cs += __shfl_xor(cs, 16, 64);
        cs += __shfl_xor(cs, 32, 64);
        if (lhi == 0)
          atomicAdd(&rowsum[colbase + wcol + ct * 16 + llo], cs);
      }
    }
  }

  // reduce the 16 lanes (llo) sharing each row, then one atomic per row
#pragma unroll
  for (int rt = 0; rt < 4; ++rt) {
#pragma unroll
    for (int g = 0; g < 4; ++g) {
      float s = rowp[rt][g];
      s += __shfl_xor(s, 1, 64);
      s += __shfl_xor(s, 2, 64);
      s += __shfl_xor(s, 4, 64);
      s += __shfl_xor(s, 8, 64);
      if (llo == 0)
        atomicAdd(&rowsum[rowbase + wrow + rt * 16 + lhi * 4 + g], s);
    }
  }
}

// ---------------- K4a: parallel reduction stage 1 ----------------
__global__ __launch_bounds__(256) void k_reduce(
    const float* __restrict__ rowsum, const float* __restrict__ pos_partial,
    float* __restrict__ blkpart) {
  __shared__ float red[256];
  const int gid = blockIdx.x * 256 + threadIdx.x;
  const int stride = RED_BLOCKS * 256;
  float s = 0.0f;
  for (int r = gid; r < TWO_B; r += stride) s += 8.0f * logf(rowsum[r] + LOSS_EPS);
  for (int k = gid; k < N_POS_WAVES; k += stride) s -= pos_partial[k];
  red[threadIdx.x] = s;
  __syncthreads();
  for (int st = 128; st > 0; st >>= 1) {
    if (threadIdx.x < st) red[threadIdx.x] += red[threadIdx.x + st];
    __syncthreads();
  }
  if (threadIdx.x == 0) blkpart[blockIdx.x] = red[0];
}

// ---------------- K4b: final scalar ----------------
__global__ __launch_bounds__(64) void k_final(
    const float* __restrict__ blkpart, float* __restrict__ out) {
  float s = threadIdx.x < RED_BLOCKS ? blkpart[threadIdx.x] : 0.0f;
#pragma unroll
  for (int m = 1; m < 64; m <<= 1) s += __shfl_xor(s, m, 64);
  if (threadIdx.x == 0) out[0] = s * (1.0f / 65536.0f);
}

extern "C" void kernel_launch(void* const* d_in, const int* in_sizes, int n_in,
                              void* d_out, int out_size, void* d_ws, size_t ws_size,
                              hipStream_t stream) {
  const float* z1 = (const float*)d_in[0];
  const float* z2 = (const float*)d_in[1];
  const float* zn = (const float*)d_in[2];
  float* out = (float*)d_out;

  char* ws = (char*)d_ws;
  __hip_bfloat16* za_n = (__hip_bfloat16*)ws;                          // 2 MB
  float* inv_za = (float*)(ws + 2097152);                              // 32 KB
  float* inv_zn = (float*)(ws + 2097152 + 32768);                      // 64 KB
  float* rowsum = (float*)(ws + 2097152 + 32768 + 65536);              // 32 KB
  float* pos_partial = (float*)(ws + 2097152 + 32768 + 65536 + 32768); // 160 KB
  float* blkpart = (float*)(ws + 2097152 + 32768 + 65536 + 32768 + 163840); // 256 B

  k_normalize<<<(TWO_B + NB) / 4, 256, 0, stream>>>(z1, z2, zn, za_n, inv_za, inv_zn);
  k_zero<<<(TWO_B + 255) / 256, 256, 0, stream>>>(rowsum);
  k_positives<<<N_POS_WAVES / 4, 256, 0, stream>>>(z1, z2, zn, inv_za, inv_zn, pos_partial);
  k_gram<<<dim3(16, 64), 256, 0, stream>>>(za_n, rowsum);
  k_reduce<<<RED_BLOCKS, 256, 0, stream>>>(rowsum, pos_partial, blkpart);
  k_final<<<1, 64, 0, stream>>>(blkpart, out);
}